// Round 4
// baseline (121.813 us; speedup 1.0000x reference)
//
#include <hip/hip_runtime.h>
#include <hip/hip_bf16.h>

#define N_ROWS 8192
#define D_DIM  512
#define NT     16   // K-tiles of BK=32

typedef __attribute__((ext_vector_type(8))) short short8;
typedef __attribute__((ext_vector_type(4))) float f32x4;

typedef const __attribute__((address_space(1))) void* gptr_t;
typedef __attribute__((address_space(3))) void* lptr_t;

static __device__ __forceinline__ void gload16(const void* g, void* l) {
    __builtin_amdgcn_global_load_lds((gptr_t)g, (lptr_t)l, 16, 0, 0);
}
#define VMCNT(n)  asm volatile("s_waitcnt vmcnt(" #n ")" ::: "memory")
#define BARRIER() __builtin_amdgcn_s_barrier()
#define SCHED0()  __builtin_amdgcn_sched_barrier(0)

// round-to-nearest-even f32 -> bf16 bits
static __device__ __forceinline__ unsigned short f2bf(float x) {
    unsigned u = __float_as_uint(x);
    unsigned r = (u + 0x7FFFu + ((u >> 16) & 1u)) >> 16;
    return (unsigned short)r;
}

// One wave per row-index i: L2-normalize cxr_i and ehr_i, write bf16,
// and compute diag_i = dot(cxr_i, ehr_i)*inva*invb/temp (full fp32) in one pass.
__global__ void normdiag_kernel(const float* __restrict__ cxr, const float* __restrict__ ehr,
                                unsigned short* __restrict__ Ab, unsigned short* __restrict__ Bb,
                                const float* __restrict__ temp, float* __restrict__ dg) {
    const int row = blockIdx.x * 4 + (threadIdx.x >> 6);
    const int lane = threadIdx.x & 63;
    const float4* a4 = (const float4*)(cxr + (size_t)row * D_DIM + lane * 8);
    const float4* b4 = (const float4*)(ehr + (size_t)row * D_DIM + lane * 8);
    float4 a0 = a4[0], a1 = a4[1];
    float4 b0 = b4[0], b1 = b4[1];
    float sa = a0.x*a0.x + a0.y*a0.y + a0.z*a0.z + a0.w*a0.w
             + a1.x*a1.x + a1.y*a1.y + a1.z*a1.z + a1.w*a1.w;
    float sb = b0.x*b0.x + b0.y*b0.y + b0.z*b0.z + b0.w*b0.w
             + b1.x*b1.x + b1.y*b1.y + b1.z*b1.z + b1.w*b1.w;
    float dt = a0.x*b0.x + a0.y*b0.y + a0.z*b0.z + a0.w*b0.w
             + a1.x*b1.x + a1.y*b1.y + a1.z*b1.z + a1.w*b1.w;
#pragma unroll
    for (int s = 1; s < 64; s <<= 1) {
        sa += __shfl_xor(sa, s);
        sb += __shfl_xor(sb, s);
        dt += __shfl_xor(dt, s);
    }
    const float ia = 1.0f / sqrtf(fmaxf(sa, 1e-16f));
    const float ib = 1.0f / sqrtf(fmaxf(sb, 1e-16f));
    if (lane == 0) dg[row] = dt * ia * ib / temp[0];
    float va[8] = {a0.x, a0.y, a0.z, a0.w, a1.x, a1.y, a1.z, a1.w};
    float vb[8] = {b0.x, b0.y, b0.z, b0.w, b1.x, b1.y, b1.z, b1.w};
    short8 oa, ob;
#pragma unroll
    for (int j = 0; j < 8; ++j) {
        oa[j] = (short)f2bf(va[j] * ia);
        ob[j] = (short)f2bf(vb[j] * ib);
    }
    *(short8*)(Ab + (size_t)row * D_DIM + lane * 8) = oa;
    *(short8*)(Bb + (size_t)row * D_DIM + lane * 8) = ob;
}

// 256x256 bf16 MFMA tile, BK=32, 8 waves (2x4), 4-deep LDS ring, counted vmcnt,
// T2 slot-swizzle (0 bank conflicts), and a cross-phase REGISTER pipeline:
// every MFMA cluster consumes fragments ds_read one phase earlier, so LDS reads
// overlap MFMA instead of serializing behind the barrier.
__global__ __launch_bounds__(512, 2) void gemm_lse_kernel(
        const unsigned short* __restrict__ A, const unsigned short* __restrict__ B,
        const float* __restrict__ temp,
        float* __restrict__ row_sum, float* __restrict__ col_sum) {
    __shared__ short As[4][8192];   // 4 x [256 rows][32 cols] bf16 = 64 KB
    __shared__ short Bs[4][8192];   // 64 KB
    __shared__ float rs_l[256];
    __shared__ float cs_l[256];

    const int tid = threadIdx.x;
    const int lane = tid & 63;
    const int wid = tid >> 6;
    const int bm = blockIdx.x, bn = blockIdx.y;
    const int wm = wid >> 2, wn = wid & 3;   // 2 x 4 wave grid; wave tile 128x64

    if (tid < 256) { rs_l[tid] = 0.f; cs_l[tid] = 0.f; }

    // staging: lane l writes LDS row (wid*16 + l>>2), slot (l&3); its global
    // source slot is (l&3)^((l>>3)&3)  [T2 involution; LDS dest stays linear]
    const int srow = wid * 16 + (lane >> 2);
    const int scol = ((lane & 3) ^ ((lane >> 3) & 3)) * 8;
    const unsigned short* gA = A + (size_t)(bm * 256 + srow) * D_DIM + scol;
    const unsigned short* gB = B + (size_t)(bn * 256 + srow) * D_DIM + scol;

#define STAGE_A(bf, t) do { \
    gload16(gA + (t) * 32,                &As[bf][wid * 512]); \
    gload16(gA + (t) * 32 + 128 * D_DIM,  &As[bf][4096 + wid * 512]); } while (0)
#define STAGE_B(bf, t) do { \
    gload16(gB + (t) * 32,                &Bs[bf][wid * 512]); \
    gload16(gB + (t) * 32 + 128 * D_DIM,  &Bs[bf][4096 + wid * 512]); } while (0)

    // read: want global slot (lane>>4) of row (.. + lr); LDS slot = g ^ ((lr>>1)&3)
    const int lr = lane & 15;
    const int g8s = (((lane >> 4) ^ ((lane >> 1) & 3)) & 3) * 8;
#define LDA(bf, m) (*(const short8*)&As[bf][(wm * 128 + (m) * 16 + lr) * 32 + g8s])
#define LDB(bf, n) (*(const short8*)&Bs[bf][(wn * 64  + (n) * 16 + lr) * 32 + g8s])

    // prologue: stage tiles 0..2 (12 loads/wave); need tiles 0 AND 1 landed for
    // the cross-tile register pipeline -> vmcnt(4) leaves only stage(2) flying.
    STAGE_A(0, 0); STAGE_B(0, 0);
    STAGE_A(1, 1); STAGE_B(1, 1);
    STAGE_A(2, 2); STAGE_B(2, 2);

    f32x4 acc[8][4] = {};

    VMCNT(4);
    BARRIER();
    SCHED0();

    short8 A03[2][4], Bf[2][4], A47[4];
#pragma unroll
    for (int m = 0; m < 4; ++m) A03[0][m] = LDA(0, m);
#pragma unroll
    for (int n = 0; n < 4; ++n) Bf[0][n] = LDB(0, n);

    // steady-state invariant entering K-tile t: buf[t], buf[t+1] globally
    // resident; regs hold A03(t), B(t); my stage(t+2) is the only outstanding.
#pragma unroll
    for (int t = 0; t < NT; ++t) {
        const int b = t & 3, nb = (t + 3) & 3, cur = t & 1, nxt = cur ^ 1;

        // ---- phase A: stage A(t+3); read A47(t); MFMA m0-3 (deps: prev phase) ----
        if (t + 3 < NT) STAGE_A(nb, t + 3);
#pragma unroll
        for (int m = 0; m < 4; ++m) A47[m] = LDA(b, m + 4);
        __builtin_amdgcn_s_setprio(1);
#pragma unroll
        for (int m = 0; m < 4; ++m)
#pragma unroll
            for (int n = 0; n < 4; ++n)
                acc[m][n] = __builtin_amdgcn_mfma_f32_16x16x32_bf16(A03[cur][m], Bf[cur][n], acc[m][n], 0, 0, 0);
        __builtin_amdgcn_s_setprio(0);

        // ---- phase B: stage B(t+3); read next tile's B + A03; MFMA m4-7 ----
        if (t + 3 < NT) STAGE_B(nb, t + 3);
        if (t < NT - 1) {
            const int b1 = (t + 1) & 3;
#pragma unroll
            for (int n = 0; n < 4; ++n) Bf[nxt][n] = LDB(b1, n);
#pragma unroll
            for (int m = 0; m < 4; ++m) A03[nxt][m] = LDA(b1, m);
        }
        __builtin_amdgcn_s_setprio(1);
#pragma unroll
        for (int m = 0; m < 4; ++m)
#pragma unroll
            for (int n = 0; n < 4; ++n)
                acc[m + 4][n] = __builtin_amdgcn_mfma_f32_16x16x32_bf16(A47[m], Bf[cur][n], acc[m + 4][n], 0, 0, 0);
        __builtin_amdgcn_s_setprio(0);

        // ---- end-of-tile: guarantee buf[t+2] landed for ALL waves; keep rest flying ----
        if (t < NT - 1) {
            if (t <= 12) VMCNT(4);   // outstanding: stage(t+2)(4) + stage(t+3)(4) -> wait t+2
            else         VMCNT(0);   // tail: stages long since issued, drain is ~free
            BARRIER();
            SCHED0();
        }
    }

    // ---- epilogue: exp + masked diag + row/col reduction ----
    const float invT = 1.0f / temp[0];
    const bool diagBlk = (bm == bn);

    float rowpart[32];
#pragma unroll
    for (int i = 0; i < 32; ++i) rowpart[i] = 0.f;
    float colpart[4] = {0.f, 0.f, 0.f, 0.f};

#pragma unroll
    for (int m = 0; m < 8; ++m)
#pragma unroll
        for (int n = 0; n < 4; ++n) {
            f32x4 a = acc[m][n];
#pragma unroll
            for (int r = 0; r < 4; ++r) {
                float e = __expf((a[r] - 1.0f) * invT);
                if (diagBlk) {
                    int grow = wm * 128 + m * 16 + (lane >> 4) * 4 + r;
                    int gcol = wn * 64 + n * 16 + (lane & 15);
                    if (grow == gcol) e = 0.f;
                }
                rowpart[m * 4 + r] += e;
                colpart[n] += e;
            }
        }

#pragma unroll
    for (int n = 0; n < 4; ++n) {
        float v = colpart[n];
        v += __shfl_xor(v, 16);
        v += __shfl_xor(v, 32);
        if (lane < 16) atomicAdd(&cs_l[wn * 64 + n * 16 + lane], v);
    }
#pragma unroll
    for (int idx = 0; idx < 32; ++idx) {
        float v = rowpart[idx];
        v += __shfl_xor(v, 1);
        v += __shfl_xor(v, 2);
        v += __shfl_xor(v, 4);
        v += __shfl_xor(v, 8);
        if ((lane & 15) == 0)
            atomicAdd(&rs_l[wm * 128 + (idx >> 2) * 16 + (lane >> 4) * 4 + (idx & 3)], v);
    }
    __syncthreads();
    if (tid < 256) atomicAdd(&row_sum[bm * 256 + tid], rs_l[tid]);
    else           atomicAdd(&col_sum[bn * 256 + (tid - 256)], cs_l[tid - 256]);
}

// loss = mean_i [ 2M + log(rs_i) + log(cs_i) - 2*diag_i ],  M = 1/temp
__global__ void finalize_kernel(const float* __restrict__ rs, const float* __restrict__ cs,
                                const float* __restrict__ dg, const float* __restrict__ temp,
                                float* __restrict__ out) {
    const float M = 1.0f / temp[0];
    float acc = 0.f;
    for (int i = threadIdx.x; i < N_ROWS; i += 256)
        acc += 2.f * M + __logf(rs[i]) + __logf(cs[i]) - 2.f * dg[i];
#pragma unroll
    for (int s = 1; s < 64; s <<= 1) acc += __shfl_xor(acc, s);
    __shared__ float wsum[4];
    if ((threadIdx.x & 63) == 0) wsum[threadIdx.x >> 6] = acc;
    __syncthreads();
    if (threadIdx.x == 0)
        out[0] = (wsum[0] + wsum[1] + wsum[2] + wsum[3]) / (float)N_ROWS;
}

extern "C" void kernel_launch(void* const* d_in, const int* in_sizes, int n_in,
                              void* d_out, int out_size, void* d_ws, size_t ws_size,
                              hipStream_t stream) {
    const float* cxr = (const float*)d_in[0];
    const float* ehr = (const float*)d_in[1];
    const float* temp = (const float*)d_in[2];
    float* out = (float*)d_out;

    char* ws = (char*)d_ws;
    unsigned short* Ab = (unsigned short*)ws;                          // 8 MB
    unsigned short* Bb = (unsigned short*)(ws + 8u * 1024 * 1024);     // 8 MB
    float* rs = (float*)(ws + 16u * 1024 * 1024);
    float* cs = rs + N_ROWS;
    float* dg = cs + N_ROWS;

    hipMemsetAsync(rs, 0, 2 * N_ROWS * sizeof(float), stream);
    normdiag_kernel<<<dim3(N_ROWS / 4), 256, 0, stream>>>(cxr, ehr, Ab, Bb, temp, dg);
    gemm_lse_kernel<<<dim3(32, 32), 512, 0, stream>>>(Ab, Bb, temp, rs, cs);
    finalize_kernel<<<1, 256, 0, stream>>>(rs, cs, dg, temp, out);
}

// Round 5
// 117.932 us; speedup vs baseline: 1.0329x; 1.0329x over previous
//
#include <hip/hip_runtime.h>
#include <hip/hip_bf16.h>

#define N_ROWS 8192
#define D_DIM  512
#define NSTEPS 8    // K-steps of BK=64

typedef __attribute__((ext_vector_type(8))) short short8;
typedef __attribute__((ext_vector_type(4))) float f32x4;

typedef const __attribute__((address_space(1))) void* gptr_t;
typedef __attribute__((address_space(3))) void* lptr_t;

static __device__ __forceinline__ void gload16(const void* g, void* l) {
    __builtin_amdgcn_global_load_lds((gptr_t)g, (lptr_t)l, 16, 0, 0);
}
#define VMCNT(n)  asm volatile("s_waitcnt vmcnt(" #n ")" ::: "memory")
#define LGKM0()   asm volatile("s_waitcnt lgkmcnt(0)" ::: "memory")
#define BARRIER() __builtin_amdgcn_s_barrier()
#define SCHED0()  __builtin_amdgcn_sched_barrier(0)
#define MFMA(a, b, c) __builtin_amdgcn_mfma_f32_16x16x32_bf16(a, b, c, 0, 0, 0)

// round-to-nearest-even f32 -> bf16 bits
static __device__ __forceinline__ unsigned short f2bf(float x) {
    unsigned u = __float_as_uint(x);
    unsigned r = (u + 0x7FFFu + ((u >> 16) & 1u)) >> 16;
    return (unsigned short)r;
}

// One wave per row-index i: L2-normalize cxr_i and ehr_i, write bf16,
// and compute diag_i = dot(cxr_i, ehr_i)*inva*invb/temp (full fp32) in one pass.
__global__ void normdiag_kernel(const float* __restrict__ cxr, const float* __restrict__ ehr,
                                unsigned short* __restrict__ Ab, unsigned short* __restrict__ Bb,
                                const float* __restrict__ temp, float* __restrict__ dg) {
    const int row = blockIdx.x * 4 + (threadIdx.x >> 6);
    const int lane = threadIdx.x & 63;
    const float4* a4 = (const float4*)(cxr + (size_t)row * D_DIM + lane * 8);
    const float4* b4 = (const float4*)(ehr + (size_t)row * D_DIM + lane * 8);
    float4 a0 = a4[0], a1 = a4[1];
    float4 b0 = b4[0], b1 = b4[1];
    float sa = a0.x*a0.x + a0.y*a0.y + a0.z*a0.z + a0.w*a0.w
             + a1.x*a1.x + a1.y*a1.y + a1.z*a1.z + a1.w*a1.w;
    float sb = b0.x*b0.x + b0.y*b0.y + b0.z*b0.z + b0.w*b0.w
             + b1.x*b1.x + b1.y*b1.y + b1.z*b1.z + b1.w*b1.w;
    float dt = a0.x*b0.x + a0.y*b0.y + a0.z*b0.z + a0.w*b0.w
             + a1.x*b1.x + a1.y*b1.y + a1.z*b1.z + a1.w*b1.w;
#pragma unroll
    for (int s = 1; s < 64; s <<= 1) {
        sa += __shfl_xor(sa, s);
        sb += __shfl_xor(sb, s);
        dt += __shfl_xor(dt, s);
    }
    const float ia = 1.0f / sqrtf(fmaxf(sa, 1e-16f));
    const float ib = 1.0f / sqrtf(fmaxf(sb, 1e-16f));
    if (lane == 0) dg[row] = dt * ia * ib / temp[0];
    float va[8] = {a0.x, a0.y, a0.z, a0.w, a1.x, a1.y, a1.z, a1.w};
    float vb[8] = {b0.x, b0.y, b0.z, b0.w, b1.x, b1.y, b1.z, b1.w};
    short8 oa, ob;
#pragma unroll
    for (int j = 0; j < 8; ++j) {
        oa[j] = (short)f2bf(va[j] * ia);
        ob[j] = (short)f2bf(vb[j] * ib);
    }
    *(short8*)(Ab + (size_t)row * D_DIM + lane * 8) = oa;
    *(short8*)(Bb + (size_t)row * D_DIM + lane * 8) = ob;
}

// m201-style 8-phase 256x256 GEMM, BK=64, 8 waves (2Mx4N), 2 double-buffers,
// 4 phases per K-step (one C-quadrant each, K+=64), counted vmcnt(4) at step
// boundaries only, T2 slot^row&7 swizzle (both sides), setprio around MFMA.
// Epilogue: exp((cos-1)/T), diag zeroed, row/col sums -> global atomics.
__global__ __launch_bounds__(512, 2) void gemm_lse_kernel(
        const unsigned short* __restrict__ A, const unsigned short* __restrict__ B,
        const float* __restrict__ temp,
        float* __restrict__ row_sum, float* __restrict__ col_sum) {
    __shared__ short As[2][16384];   // [buf][256 rows][64 cols] bf16 = 2 x 32 KB
    __shared__ short Bs[2][16384];
    __shared__ float rs_l[256];
    __shared__ float cs_l[256];

    const int tid = threadIdx.x;
    const int lane = tid & 63;
    const int wid = tid >> 6;
    const int bm = blockIdx.x, bn = blockIdx.y;
    const int wm = wid >> 2, wn = wid & 3;   // wave tile 128x64

    if (tid < 256) { rs_l[tid] = 0.f; cs_l[tid] = 0.f; }

    // ---- staging geometry: half-tile = 128 rows x 64 K of one matrix = 16 KB
    // wave w stages rows w*16..w*16+15 of the half via 2 gloads (8 rows each).
    // LDS write is linear (base + lane*16); swizzle goes on the SOURCE column:
    // lane l covers LDS row r0+l>>3, slot l&7; its global slot = (l&7)^(l>>3).
    const int l8 = lane >> 3, l7 = lane & 7;
    const unsigned short* gA = A + (size_t)(bm * 256 + wid * 16 + l8) * D_DIM + (l7 ^ l8) * 8;
    const unsigned short* gB = B + (size_t)(bn * 256 + wid * 16 + l8) * D_DIM + (l7 ^ l8) * 8;

#define STG_A(d, h, s) do { \
    gload16(gA + (size_t)((h) * 128    ) * D_DIM + (s) * 64, &As[d][((h) * 128 + wid * 16    ) * 64]); \
    gload16(gA + (size_t)((h) * 128 + 8) * D_DIM + (s) * 64, &As[d][((h) * 128 + wid * 16 + 8) * 64]); } while (0)
#define STG_B(d, h, s) do { \
    gload16(gB + (size_t)((h) * 128    ) * D_DIM + (s) * 64, &Bs[d][((h) * 128 + wid * 16    ) * 64]); \
    gload16(gB + (size_t)((h) * 128 + 8) * D_DIM + (s) * 64, &Bs[d][((h) * 128 + wid * 16 + 8) * 64]); } while (0)

    // ---- fragment reads: row r, K-frag kf, K-half g: LDS slot = (kf*4+g)^(r&7)
    const int lr = lane & 15, g = lane >> 4;
    const int sw0 = ((g ^ (lr & 7)) & 7) * 8;            // kf=0
    const int sw1 = (((4 + g) ^ (lr & 7)) & 7) * 8;      // kf=1
#define RDA0(d, r) (*(const short8*)&As[d][(r) * 64 + sw0])
#define RDA1(d, r) (*(const short8*)&As[d][(r) * 64 + sw1])
#define RDB0(d, r) (*(const short8*)&Bs[d][(r) * 64 + sw0])
#define RDB1(d, r) (*(const short8*)&Bs[d][(r) * 64 + sw1])

    f32x4 acc[8][4] = {};
    short8 Ar[4][2], Bq0[2][2], Bq1[2][2];

    // ---- prologue: stage in vmcnt-ledger order: step0 (4 half-tiles), then B of step1
    STG_B(0, 0, 0); STG_B(0, 1, 0);
    STG_A(0, 0, 0); STG_A(0, 1, 0);
    STG_B(1, 0, 1); STG_B(1, 1, 1);

#pragma unroll
    for (int s = 0; s < NSTEPS; ++s) {
        const int d = s & 1;

        // ---- K-step boundary: certify step s's stages landed for ALL waves.
        // Outstanding after wait: the 2 newest half-tiles (B of step s+1). Never 0
        // until the tail (no stages left to cover).
        if (s < NSTEPS - 1) VMCNT(4); else VMCNT(0);
        BARRIER(); SCHED0();

        // ======== phase q0: quadrant (qr0,qc0) ========
#pragma unroll
        for (int mi = 0; mi < 4; ++mi) {
            Ar[mi][0] = RDA0(d, wm * 128 + mi * 16 + lr);
            Ar[mi][1] = RDA1(d, wm * 128 + mi * 16 + lr);
        }
#pragma unroll
        for (int ni = 0; ni < 2; ++ni) {
            Bq0[ni][0] = RDB0(d, wn * 64 + ni * 16 + lr);
            Bq0[ni][1] = RDB1(d, wn * 64 + ni * 16 + lr);
        }
        if (s + 1 < NSTEPS) STG_A(d ^ 1, 0, s + 1);
        BARRIER();
        LGKM0(); SCHED0();
        __builtin_amdgcn_s_setprio(1);
#pragma unroll
        for (int mi = 0; mi < 4; ++mi)
#pragma unroll
            for (int ni = 0; ni < 2; ++ni) {
                acc[mi][ni] = MFMA(Ar[mi][0], Bq0[ni][0], acc[mi][ni]);
                acc[mi][ni] = MFMA(Ar[mi][1], Bq0[ni][1], acc[mi][ni]);
            }
        __builtin_amdgcn_s_setprio(0);
        BARRIER();

        // ======== phase q1: quadrant (qr0,qc1) ========
#pragma unroll
        for (int ni = 0; ni < 2; ++ni) {
            Bq1[ni][0] = RDB0(d, wn * 64 + 32 + ni * 16 + lr);
            Bq1[ni][1] = RDB1(d, wn * 64 + 32 + ni * 16 + lr);
        }
        if (s + 1 < NSTEPS) STG_A(d ^ 1, 1, s + 1);
        BARRIER();
        LGKM0(); SCHED0();
        __builtin_amdgcn_s_setprio(1);
#pragma unroll
        for (int mi = 0; mi < 4; ++mi)
#pragma unroll
            for (int ni = 0; ni < 2; ++ni) {
                acc[mi][2 + ni] = MFMA(Ar[mi][0], Bq1[ni][0], acc[mi][2 + ni]);
                acc[mi][2 + ni] = MFMA(Ar[mi][1], Bq1[ni][1], acc[mi][2 + ni]);
            }
        __builtin_amdgcn_s_setprio(0);
        BARRIER();

        // ======== phase q2: quadrant (qr1,qc0); Ar regs recycled ========
#pragma unroll
        for (int mi = 0; mi < 4; ++mi) {
            Ar[mi][0] = RDA0(d, wm * 128 + 64 + mi * 16 + lr);
            Ar[mi][1] = RDA1(d, wm * 128 + 64 + mi * 16 + lr);
        }
        if (s + 2 < NSTEPS) STG_B(d, 0, s + 2);   // B slots of buf d freed after q1
        BARRIER();
        LGKM0(); SCHED0();
        __builtin_amdgcn_s_setprio(1);
#pragma unroll
        for (int mi = 0; mi < 4; ++mi)
#pragma unroll
            for (int ni = 0; ni < 2; ++ni) {
                acc[4 + mi][ni] = MFMA(Ar[mi][0], Bq0[ni][0], acc[4 + mi][ni]);
                acc[4 + mi][ni] = MFMA(Ar[mi][1], Bq0[ni][1], acc[4 + mi][ni]);
            }
        __builtin_amdgcn_s_setprio(0);
        BARRIER();

        // ======== phase q3: quadrant (qr1,qc1); no new ds_reads ========
        if (s + 2 < NSTEPS) STG_B(d, 1, s + 2);
        BARRIER();
        SCHED0();
        __builtin_amdgcn_s_setprio(1);
#pragma unroll
        for (int mi = 0; mi < 4; ++mi)
#pragma unroll
            for (int ni = 0; ni < 2; ++ni) {
                acc[4 + mi][2 + ni] = MFMA(Ar[mi][0], Bq1[ni][0], acc[4 + mi][2 + ni]);
                acc[4 + mi][2 + ni] = MFMA(Ar[mi][1], Bq1[ni][1], acc[4 + mi][2 + ni]);
            }
        __builtin_amdgcn_s_setprio(0);
        BARRIER();
    }

    // ---- epilogue: exp + masked diag + row/col reduction ----
    const float invT = 1.0f / temp[0];
    const bool diagBlk = (bm == bn);

    float rowpart[32];
#pragma unroll
    for (int i = 0; i < 32; ++i) rowpart[i] = 0.f;
    float colpart[4] = {0.f, 0.f, 0.f, 0.f};

#pragma unroll
    for (int m = 0; m < 8; ++m)
#pragma unroll
        for (int n = 0; n < 4; ++n) {
            f32x4 a = acc[m][n];
#pragma unroll
            for (int r = 0; r < 4; ++r) {
                float e = __expf((a[r] - 1.0f) * invT);
                if (diagBlk) {
                    int grow = wm * 128 + m * 16 + (lane >> 4) * 4 + r;
                    int gcol = wn * 64 + n * 16 + (lane & 15);
                    if (grow == gcol) e = 0.f;
                }
                rowpart[m * 4 + r] += e;
                colpart[n] += e;
            }
        }

#pragma unroll
    for (int n = 0; n < 4; ++n) {
        float v = colpart[n];
        v += __shfl_xor(v, 16);
        v += __shfl_xor(v, 32);
        if (lane < 16) atomicAdd(&cs_l[wn * 64 + n * 16 + lane], v);
    }
#pragma unroll
    for (int idx = 0; idx < 32; ++idx) {
        float v = rowpart[idx];
        v += __shfl_xor(v, 1);
        v += __shfl_xor(v, 2);
        v += __shfl_xor(v, 4);
        v += __shfl_xor(v, 8);
        if ((lane & 15) == 0)
            atomicAdd(&rs_l[wm * 128 + (idx >> 2) * 16 + (lane >> 4) * 4 + (idx & 3)], v);
    }
    __syncthreads();
    if (tid < 256) atomicAdd(&row_sum[bm * 256 + tid], rs_l[tid]);
    else           atomicAdd(&col_sum[bn * 256 + (tid - 256)], cs_l[tid - 256]);
}

// loss = mean_i [ 2M + log(rs_i) + log(cs_i) - 2*diag_i ],  M = 1/temp
__global__ void finalize_kernel(const float* __restrict__ rs, const float* __restrict__ cs,
                                const float* __restrict__ dg, const float* __restrict__ temp,
                                float* __restrict__ out) {
    const float M = 1.0f / temp[0];
    float acc = 0.f;
    for (int i = threadIdx.x; i < N_ROWS; i += 256)
        acc += 2.f * M + __logf(rs[i]) + __logf(cs[i]) - 2.f * dg[i];
#pragma unroll
    for (int s = 1; s < 64; s <<= 1) acc += __shfl_xor(acc, s);
    __shared__ float wsum[4];
    if ((threadIdx.x & 63) == 0) wsum[threadIdx.x >> 6] = acc;
    __syncthreads();
    if (threadIdx.x == 0)
        out[0] = (wsum[0] + wsum[1] + wsum[2] + wsum[3]) / (float)N_ROWS;
}

extern "C" void kernel_launch(void* const* d_in, const int* in_sizes, int n_in,
                              void* d_out, int out_size, void* d_ws, size_t ws_size,
                              hipStream_t stream) {
    const float* cxr = (const float*)d_in[0];
    const float* ehr = (const float*)d_in[1];
    const float* temp = (const float*)d_in[2];
    float* out = (float*)d_out;

    char* ws = (char*)d_ws;
    unsigned short* Ab = (unsigned short*)ws;                          // 8 MB
    unsigned short* Bb = (unsigned short*)(ws + 8u * 1024 * 1024);     // 8 MB
    float* rs = (float*)(ws + 16u * 1024 * 1024);
    float* cs = rs + N_ROWS;
    float* dg = cs + N_ROWS;

    hipMemsetAsync(rs, 0, 2 * N_ROWS * sizeof(float), stream);
    normdiag_kernel<<<dim3(N_ROWS / 4), 256, 0, stream>>>(cxr, ehr, Ab, Bb, temp, dg);
    gemm_lse_kernel<<<dim3(32, 32), 512, 0, stream>>>(Ab, Bb, temp, rs, cs);
    finalize_kernel<<<1, 256, 0, stream>>>(rs, cs, dg, temp, out);
}

// Round 6
// 116.831 us; speedup vs baseline: 1.0426x; 1.0094x over previous
//
#include <hip/hip_runtime.h>
#include <hip/hip_bf16.h>

#define N_ROWS 8192
#define D_DIM  512
#define NSTEPS 8    // K-steps of BK=64

typedef __attribute__((ext_vector_type(8))) short short8;
typedef __attribute__((ext_vector_type(4))) float f32x4;

typedef const __attribute__((address_space(1))) void* gptr_t;
typedef __attribute__((address_space(3))) void* lptr_t;

static __device__ __forceinline__ void gload16(const void* g, void* l) {
    __builtin_amdgcn_global_load_lds((gptr_t)g, (lptr_t)l, 16, 0, 0);
}
#define VMCNT(n)  asm volatile("s_waitcnt vmcnt(" #n ")" ::: "memory")
#define LGKM0()   asm volatile("s_waitcnt lgkmcnt(0)" ::: "memory")
#define BARRIER() __builtin_amdgcn_s_barrier()
#define SCHED0()  __builtin_amdgcn_sched_barrier(0)
#define MFMA(a, b, c) __builtin_amdgcn_mfma_f32_16x16x32_bf16(a, b, c, 0, 0, 0)

// round-to-nearest-even f32 -> bf16 bits
static __device__ __forceinline__ unsigned short f2bf(float x) {
    unsigned u = __float_as_uint(x);
    unsigned r = (u + 0x7FFFu + ((u >> 16) & 1u)) >> 16;
    return (unsigned short)r;
}

// One wave per row-index i: L2-normalize cxr_i and ehr_i, write bf16,
// and compute diag_i = dot(cxr_i, ehr_i)*inva*invb/temp (full fp32) in one pass.
__global__ void normdiag_kernel(const float* __restrict__ cxr, const float* __restrict__ ehr,
                                unsigned short* __restrict__ Ab, unsigned short* __restrict__ Bb,
                                const float* __restrict__ temp, float* __restrict__ dg) {
    const int row = blockIdx.x * 4 + (threadIdx.x >> 6);
    const int lane = threadIdx.x & 63;
    const float4* a4 = (const float4*)(cxr + (size_t)row * D_DIM + lane * 8);
    const float4* b4 = (const float4*)(ehr + (size_t)row * D_DIM + lane * 8);
    float4 a0 = a4[0], a1 = a4[1];
    float4 b0 = b4[0], b1 = b4[1];
    float sa = a0.x*a0.x + a0.y*a0.y + a0.z*a0.z + a0.w*a0.w
             + a1.x*a1.x + a1.y*a1.y + a1.z*a1.z + a1.w*a1.w;
    float sb = b0.x*b0.x + b0.y*b0.y + b0.z*b0.z + b0.w*b0.w
             + b1.x*b1.x + b1.y*b1.y + b1.z*b1.z + b1.w*b1.w;
    float dt = a0.x*b0.x + a0.y*b0.y + a0.z*b0.z + a0.w*b0.w
             + a1.x*b1.x + a1.y*b1.y + a1.z*b1.z + a1.w*b1.w;
#pragma unroll
    for (int s = 1; s < 64; s <<= 1) {
        sa += __shfl_xor(sa, s);
        sb += __shfl_xor(sb, s);
        dt += __shfl_xor(dt, s);
    }
    const float ia = 1.0f / sqrtf(fmaxf(sa, 1e-16f));
    const float ib = 1.0f / sqrtf(fmaxf(sb, 1e-16f));
    if (lane == 0) dg[row] = dt * ia * ib / temp[0];
    float va[8] = {a0.x, a0.y, a0.z, a0.w, a1.x, a1.y, a1.z, a1.w};
    float vb[8] = {b0.x, b0.y, b0.z, b0.w, b1.x, b1.y, b1.z, b1.w};
    short8 oa, ob;
#pragma unroll
    for (int j = 0; j < 8; ++j) {
        oa[j] = (short)f2bf(va[j] * ia);
        ob[j] = (short)f2bf(vb[j] * ib);
    }
    *(short8*)(Ab + (size_t)row * D_DIM + lane * 8) = oa;
    *(short8*)(Bb + (size_t)row * D_DIM + lane * 8) = ob;
}

// m201-style 8-phase 256x256 GEMM (inner loop IDENTICAL to r5) with XCD
// supertiling: XCD x owns bn in [4x,4x+4), walked bm-group-major, so its 4
// B panels (1MB) stay L2-resident and each A panel is L3-fetched once per XCD.
__global__ __launch_bounds__(512, 2) void gemm_lse_kernel(
        const unsigned short* __restrict__ A, const unsigned short* __restrict__ B,
        const float* __restrict__ temp,
        float* __restrict__ row_sum, float* __restrict__ col_sum) {
    __shared__ short As[2][16384];   // [buf][256 rows][64 cols] bf16 = 2 x 32 KB
    __shared__ short Bs[2][16384];
    __shared__ float rs_l[256];
    __shared__ float cs_l[256];

    const int tid = threadIdx.x;
    const int lane = tid & 63;
    const int wid = tid >> 6;
    // XCD-locality remap: consecutive blockIdx round-robin across 8 XCDs.
    const int xcd = blockIdx.x & 7;
    const int slot = blockIdx.x >> 3;          // 0..127 per XCD
    const int bm = slot >> 2;                  // 0..31
    const int bn = xcd * 4 + (slot & 3);       // 0..31, XCD-owned band
    const int wm = wid >> 2, wn = wid & 3;     // wave tile 128x64

    if (tid < 256) { rs_l[tid] = 0.f; cs_l[tid] = 0.f; }

    // staging: lane l covers LDS row r0+l>>3, slot l&7; global slot = (l&7)^(l>>3)
    const int l8 = lane >> 3, l7 = lane & 7;
    const unsigned short* gA = A + (size_t)(bm * 256 + wid * 16 + l8) * D_DIM + (l7 ^ l8) * 8;
    const unsigned short* gB = B + (size_t)(bn * 256 + wid * 16 + l8) * D_DIM + (l7 ^ l8) * 8;

#define STG_A(d, h, s) do { \
    gload16(gA + (size_t)((h) * 128    ) * D_DIM + (s) * 64, &As[d][((h) * 128 + wid * 16    ) * 64]); \
    gload16(gA + (size_t)((h) * 128 + 8) * D_DIM + (s) * 64, &As[d][((h) * 128 + wid * 16 + 8) * 64]); } while (0)
#define STG_B(d, h, s) do { \
    gload16(gB + (size_t)((h) * 128    ) * D_DIM + (s) * 64, &Bs[d][((h) * 128 + wid * 16    ) * 64]); \
    gload16(gB + (size_t)((h) * 128 + 8) * D_DIM + (s) * 64, &Bs[d][((h) * 128 + wid * 16 + 8) * 64]); } while (0)

    // fragment reads: row r, K-frag kf, K-half g: LDS slot = (kf*4+g)^(r&7)
    const int lr = lane & 15, g = lane >> 4;
    const int sw0 = ((g ^ (lr & 7)) & 7) * 8;            // kf=0
    const int sw1 = (((4 + g) ^ (lr & 7)) & 7) * 8;      // kf=1
#define RDA0(d, r) (*(const short8*)&As[d][(r) * 64 + sw0])
#define RDA1(d, r) (*(const short8*)&As[d][(r) * 64 + sw1])
#define RDB0(d, r) (*(const short8*)&Bs[d][(r) * 64 + sw0])
#define RDB1(d, r) (*(const short8*)&Bs[d][(r) * 64 + sw1])

    f32x4 acc[8][4] = {};
    short8 Ar[4][2], Bq0[2][2], Bq1[2][2];

    // prologue: stage step0 (4 half-tiles), then B of step1
    STG_B(0, 0, 0); STG_B(0, 1, 0);
    STG_A(0, 0, 0); STG_A(0, 1, 0);
    STG_B(1, 0, 1); STG_B(1, 1, 1);

#pragma unroll
    for (int s = 0; s < NSTEPS; ++s) {
        const int d = s & 1;

        // K-step boundary: certify step s's stages landed for ALL waves.
        if (s < NSTEPS - 1) VMCNT(4); else VMCNT(0);
        BARRIER(); SCHED0();

        // ======== phase q0 ========
#pragma unroll
        for (int mi = 0; mi < 4; ++mi) {
            Ar[mi][0] = RDA0(d, wm * 128 + mi * 16 + lr);
            Ar[mi][1] = RDA1(d, wm * 128 + mi * 16 + lr);
        }
#pragma unroll
        for (int ni = 0; ni < 2; ++ni) {
            Bq0[ni][0] = RDB0(d, wn * 64 + ni * 16 + lr);
            Bq0[ni][1] = RDB1(d, wn * 64 + ni * 16 + lr);
        }
        if (s + 1 < NSTEPS) STG_A(d ^ 1, 0, s + 1);
        BARRIER();
        LGKM0(); SCHED0();
        __builtin_amdgcn_s_setprio(1);
#pragma unroll
        for (int mi = 0; mi < 4; ++mi)
#pragma unroll
            for (int ni = 0; ni < 2; ++ni) {
                acc[mi][ni] = MFMA(Ar[mi][0], Bq0[ni][0], acc[mi][ni]);
                acc[mi][ni] = MFMA(Ar[mi][1], Bq0[ni][1], acc[mi][ni]);
            }
        __builtin_amdgcn_s_setprio(0);
        BARRIER();

        // ======== phase q1 ========
#pragma unroll
        for (int ni = 0; ni < 2; ++ni) {
            Bq1[ni][0] = RDB0(d, wn * 64 + 32 + ni * 16 + lr);
            Bq1[ni][1] = RDB1(d, wn * 64 + 32 + ni * 16 + lr);
        }
        if (s + 1 < NSTEPS) STG_A(d ^ 1, 1, s + 1);
        BARRIER();
        LGKM0(); SCHED0();
        __builtin_amdgcn_s_setprio(1);
#pragma unroll
        for (int mi = 0; mi < 4; ++mi)
#pragma unroll
            for (int ni = 0; ni < 2; ++ni) {
                acc[mi][2 + ni] = MFMA(Ar[mi][0], Bq1[ni][0], acc[mi][2 + ni]);
                acc[mi][2 + ni] = MFMA(Ar[mi][1], Bq1[ni][1], acc[mi][2 + ni]);
            }
        __builtin_amdgcn_s_setprio(0);
        BARRIER();

        // ======== phase q2 ========
#pragma unroll
        for (int mi = 0; mi < 4; ++mi) {
            Ar[mi][0] = RDA0(d, wm * 128 + 64 + mi * 16 + lr);
            Ar[mi][1] = RDA1(d, wm * 128 + 64 + mi * 16 + lr);
        }
        if (s + 2 < NSTEPS) STG_B(d, 0, s + 2);
        BARRIER();
        LGKM0(); SCHED0();
        __builtin_amdgcn_s_setprio(1);
#pragma unroll
        for (int mi = 0; mi < 4; ++mi)
#pragma unroll
            for (int ni = 0; ni < 2; ++ni) {
                acc[4 + mi][ni] = MFMA(Ar[mi][0], Bq0[ni][0], acc[4 + mi][ni]);
                acc[4 + mi][ni] = MFMA(Ar[mi][1], Bq0[ni][1], acc[4 + mi][ni]);
            }
        __builtin_amdgcn_s_setprio(0);
        BARRIER();

        // ======== phase q3 ========
        if (s + 2 < NSTEPS) STG_B(d, 1, s + 2);
        BARRIER();
        SCHED0();
        __builtin_amdgcn_s_setprio(1);
#pragma unroll
        for (int mi = 0; mi < 4; ++mi)
#pragma unroll
            for (int ni = 0; ni < 2; ++ni) {
                acc[4 + mi][2 + ni] = MFMA(Ar[mi][0], Bq1[ni][0], acc[4 + mi][2 + ni]);
                acc[4 + mi][2 + ni] = MFMA(Ar[mi][1], Bq1[ni][1], acc[4 + mi][2 + ni]);
            }
        __builtin_amdgcn_s_setprio(0);
        BARRIER();
    }

    // ---- epilogue: exp + masked diag + row/col reduction ----
    const float invT = 1.0f / temp[0];
    const bool diagBlk = (bm == bn);

    float rowpart[32];
#pragma unroll
    for (int i = 0; i < 32; ++i) rowpart[i] = 0.f;
    float colpart[4] = {0.f, 0.f, 0.f, 0.f};

#pragma unroll
    for (int m = 0; m < 8; ++m)
#pragma unroll
        for (int n = 0; n < 4; ++n) {
            f32x4 a = acc[m][n];
#pragma unroll
            for (int r = 0; r < 4; ++r) {
                float e = __expf((a[r] - 1.0f) * invT);
                if (diagBlk) {
                    int grow = wm * 128 + m * 16 + (lane >> 4) * 4 + r;
                    int gcol = wn * 64 + n * 16 + (lane & 15);
                    if (grow == gcol) e = 0.f;
                }
                rowpart[m * 4 + r] += e;
                colpart[n] += e;
            }
        }

#pragma unroll
    for (int n = 0; n < 4; ++n) {
        float v = colpart[n];
        v += __shfl_xor(v, 16);
        v += __shfl_xor(v, 32);
        if (lane < 16) atomicAdd(&cs_l[wn * 64 + n * 16 + lane], v);
    }
#pragma unroll
    for (int idx = 0; idx < 32; ++idx) {
        float v = rowpart[idx];
        v += __shfl_xor(v, 1);
        v += __shfl_xor(v, 2);
        v += __shfl_xor(v, 4);
        v += __shfl_xor(v, 8);
        if ((lane & 15) == 0)
            atomicAdd(&rs_l[wm * 128 + (idx >> 2) * 16 + (lane >> 4) * 4 + (idx & 3)], v);
    }
    __syncthreads();
    if (tid < 256) atomicAdd(&row_sum[bm * 256 + tid], rs_l[tid]);
    else           atomicAdd(&col_sum[bn * 256 + (tid - 256)], cs_l[tid - 256]);
}

// loss = mean_i [ 2M + log(rs_i) + log(cs_i) - 2*diag_i ],  M = 1/temp
__global__ void finalize_kernel(const float* __restrict__ rs, const float* __restrict__ cs,
                                const float* __restrict__ dg, const float* __restrict__ temp,
                                float* __restrict__ out) {
    const float M = 1.0f / temp[0];
    float acc = 0.f;
    for (int i = threadIdx.x; i < N_ROWS; i += 256)
        acc += 2.f * M + __logf(rs[i]) + __logf(cs[i]) - 2.f * dg[i];
#pragma unroll
    for (int s = 1; s < 64; s <<= 1) acc += __shfl_xor(acc, s);
    __shared__ float wsum[4];
    if ((threadIdx.x & 63) == 0) wsum[threadIdx.x >> 6] = acc;
    __syncthreads();
    if (threadIdx.x == 0)
        out[0] = (wsum[0] + wsum[1] + wsum[2] + wsum[3]) / (float)N_ROWS;
}

extern "C" void kernel_launch(void* const* d_in, const int* in_sizes, int n_in,
                              void* d_out, int out_size, void* d_ws, size_t ws_size,
                              hipStream_t stream) {
    const float* cxr = (const float*)d_in[0];
    const float* ehr = (const float*)d_in[1];
    const float* temp = (const float*)d_in[2];
    float* out = (float*)d_out;

    char* ws = (char*)d_ws;
    unsigned short* Ab = (unsigned short*)ws;                          // 8 MB
    unsigned short* Bb = (unsigned short*)(ws + 8u * 1024 * 1024);     // 8 MB
    float* rs = (float*)(ws + 16u * 1024 * 1024);
    float* cs = rs + N_ROWS;
    float* dg = cs + N_ROWS;

    hipMemsetAsync(rs, 0, 2 * N_ROWS * sizeof(float), stream);
    normdiag_kernel<<<dim3(N_ROWS / 4), 256, 0, stream>>>(cxr, ehr, Ab, Bb, temp, dg);
    gemm_lse_kernel<<<dim3(1024), 512, 0, stream>>>(Ab, Bb, temp, rs, cs);
    finalize_kernel<<<1, 256, 0, stream>>>(rs, cs, dg, temp, out);
}